// Round 4
// baseline (549.973 us; speedup 1.0000x reference)
//
#include <hip/hip_runtime.h>

// Group_10: replicate-pad 3x3 conv (4,512,32,32)->(4,9728,32,32) + bias,
// then faithful-PS reinterpretation to (4,152,256,256).
//
// Implicit GEMM, pre-packed bf16 operands (pack_W / pack_A unchanged from
// round 3 — verified on HW: absmax 0.031, bank conflicts 0).
//
// Round 4: 256x256-tile 8-phase schedule (T3+T4 counted vmcnt + T5 setprio).
// 8 waves (2Mx4N), per-wave 128x64 output, BK=64, 2 K-tiles per LDS dbuf
// period, 4 phases per K-tile:
//   ph1: ds_read A[m0-3]x2kc + B[n0-1]x2kc (12) | stage B0(t+1) | bar | MFMA q0
//   ph2: ds_read B[n2-3]x2kc (4)                | stage B1(t+1) | bar | MFMA q1
//   ph3: ds_read A[m4-7]x2kc (8)                |               | bar | MFMA q2
//   ph4:                                        | stage A0,A1(t+2) | bar | MFMA q3
//        vmcnt(4)  <- keeps A(t+2) in flight, retires all of tile t+1
// Race-freedom: every stage targets a slot whose last ds_read drained
// (lgkmcnt(0)) before an earlier end-barrier. Loads never drain to 0.

#define CIN   512
#define COUT  9728
#define NBAT  4
#define KTOT  4608
#define KSTEPS 72           // K = 72 * 64
#define MB256  16           // M = 4096 = 16*256
#define NB256  38           // N = 9728 = 38*256
#define TB     16384        // packed tile: 128 rows x 64 bf16 x 2B
#define PANEL  (KSTEPS * TB)

typedef __bf16 bf16x8 __attribute__((ext_vector_type(8)));
typedef float  f32x4  __attribute__((ext_vector_type(4)));

#define BAR()   __builtin_amdgcn_s_barrier()
#define LGK0()  asm volatile("s_waitcnt lgkmcnt(0)" ::: "memory")
#define VMC4()  asm volatile("s_waitcnt vmcnt(4)" ::: "memory")
#define SCHED0() __builtin_amdgcn_sched_barrier(0)
#define PRIO1() __builtin_amdgcn_s_setprio(1)
#define PRIO0() __builtin_amdgcn_s_setprio(0)

// ---------------- fallback: direct conv (correct, slow) ----------------
__global__ __launch_bounds__(256) void conv_ps_direct(
    const float* __restrict__ x, const float* __restrict__ Wt,
    const float* __restrict__ bias, float* __restrict__ out)
{
    int flat = blockIdx.x * 256 + threadIdx.x;
    int w  = flat & 31;
    int h  = (flat >> 5) & 31;
    int t  = flat >> 10;
    int co = t % COUT;
    int b  = t / COUT;

    const float* xb = x + (size_t)b * CIN * 1024;
    const float* Wc = Wt + (size_t)co * CIN * 9;

    int hm = h > 0  ? h - 1 : 0;
    int hp = h < 31 ? h + 1 : 31;
    int wm = w > 0  ? w - 1 : 0;
    int wp = w < 31 ? w + 1 : 31;

    float acc = bias[co];
    #pragma unroll 4
    for (int ci = 0; ci < CIN; ++ci) {
        const float* xc = xb + ci * 1024;
        const float* wf = Wc + ci * 9;
        const float* r0 = xc + hm * 32;
        const float* r1 = xc + h  * 32;
        const float* r2 = xc + hp * 32;
        acc += wf[0] * r0[wm] + wf[1] * r0[w] + wf[2] * r0[wp];
        acc += wf[3] * r1[wm] + wf[4] * r1[w] + wf[5] * r1[wp];
        acc += wf[6] * r2[wm] + wf[7] * r2[w] + wf[8] * r2[wp];
    }
    int cc = co & 63;
    int n  = co >> 6;
    int i  = ((cc >> 1) << 3) | (w & 7);
    int j  = ((cc & 1) << 7) | ((h >> 1) << 3) | ((h & 1) << 2) | (w >> 3);
    out[(((size_t)b * 152 + n) * 256 + i) * 256 + j] = acc;
}

// ---------------- pack W: fp32 -> bf16, tiled + swizzled ----------------
__global__ __launch_bounds__(256) void pack_W(const float* __restrict__ Wt,
                                              __bf16* __restrict__ Wws)
{
    int G = blockIdx.x * 256 + threadIdx.x;   // < 76*72*128*8
    int s    = G & 7;
    int r    = (G >> 3) & 127;
    int rest = G >> 10;                        // nb128*72 + kt
    int kt = rest % KSTEPS;
    int nb = rest / KSTEPS;
    int n  = nb * 128 + r;
    int g  = s ^ (r & 7);
    int k0 = kt * 64 + g * 8;

    const float* src = Wt + (size_t)n * KTOT + k0;
    float4 v0 = *(const float4*)(src);
    float4 v1 = *(const float4*)(src + 4);
    bf16x8 o;
    o[0] = (__bf16)v0.x; o[1] = (__bf16)v0.y; o[2] = (__bf16)v0.z; o[3] = (__bf16)v0.w;
    o[4] = (__bf16)v1.x; o[5] = (__bf16)v1.y; o[6] = (__bf16)v1.z; o[7] = (__bf16)v1.w;
    *(bf16x8*)(Wws + (size_t)G * 8) = o;
}

// ---------------- pack A: im2col bf16, same tiling/swizzle ----------------
__global__ __launch_bounds__(256) void pack_A(const float* __restrict__ x,
                                              __bf16* __restrict__ Aws)
{
    int G = blockIdx.x * 256 + threadIdx.x;   // < 32*72*128*8
    int s    = G & 7;
    int r    = (G >> 3) & 127;
    int rest = G >> 10;                        // mb128*72 + kt
    int kt = rest % KSTEPS;
    int mb = rest / KSTEPS;
    int m  = mb * 128 + r;
    int b  = m >> 10;
    int h  = (m >> 5) & 31;
    int w  = m & 31;
    int g  = s ^ (r & 7);
    int k0 = kt * 64 + g * 8;

    const float* xb = x + (size_t)b * CIN * 1024;
    bf16x8 o;
    #pragma unroll
    for (int e = 0; e < 8; ++e) {
        int k  = k0 + e;
        int ci = k / 9;
        int r9 = k - ci * 9;
        int kh = r9 / 3;
        int kw = r9 - kh * 3;
        int hh = h + kh - 1; hh = hh < 0 ? 0 : (hh > 31 ? 31 : hh);
        int ww = w + kw - 1; ww = ww < 0 ? 0 : (ww > 31 ? 31 : ww);
        o[e] = (__bf16)xb[(ci << 10) + (hh << 5) + ww];
    }
    *(bf16x8*)(Aws + (size_t)G * 8) = o;
}

// ---------------- 256x256 8-phase GEMM + fused PS epilogue ----------------
__global__ __launch_bounds__(512, 2) void gemm_ps(
    const __bf16* __restrict__ Aws, const __bf16* __restrict__ Wws,
    const float* __restrict__ bias, float* __restrict__ out)
{
    // LDS: buf d at d*65536; A-half h at +h*16384; B-half h at +32768+h*16384
    __shared__ __align__(16) char smem[131072];

    // XCD-bijective swizzle: 608 blocks = 8 * 76
    int bid = blockIdx.x;
    int g   = (bid & 7) * 76 + (bid >> 3);
    int mb  = g & 15;          // 76 per XCD chunk = 16 mb x 4.75 nb (B reuse)
    int nb  = g >> 4;

    int t    = threadIdx.x;
    int lane = t & 63;
    int wid  = t >> 6;
    int wm = wid >> 2, wn = wid & 3;      // 2x4 waves; wave tile 128x64

    const char* Apan = (const char*)Aws + (size_t)(mb * 2) * PANEL;
    const char* Bpan = (const char*)Wws + (size_t)(nb * 2) * PANEL;
    int t16 = t * 16;

    auto stage = [&](const char* srcTile, int ldsOff) {
        __builtin_amdgcn_global_load_lds(
            (const __attribute__((address_space(1))) void*)(srcTile + t16),
            (__attribute__((address_space(3))) void*)(smem + ldsOff + t16), 16, 0, 0);
        __builtin_amdgcn_global_load_lds(
            (const __attribute__((address_space(1))) void*)(srcTile + 8192 + t16),
            (__attribute__((address_space(3))) void*)(smem + ldsOff + 8192 + t16), 16, 0, 0);
    };

    // swizzled ds_read offsets (swizzle pre-baked in global layout)
    int aoff = wm * 16384 + (lane & 15) * 128;
    int boff = 32768 + (wn >> 1) * 16384 + (((wn & 1) << 6) + (lane & 15)) * 128;
    int kx0  = (((lane >> 4)    ) ^ (lane & 7)) << 4;
    int kx1  = (((lane >> 4) + 4) ^ (lane & 7)) << 4;

    f32x4 acc[8][4] = {};
    bf16x8 af[8], bl[4], bh[4];

    // prologue: tile 0 fully + A halves of tile 1
    stage(Apan + 0 * PANEL + 0 * TB, 0);
    stage(Apan + 1 * PANEL + 0 * TB, 16384);
    stage(Bpan + 0 * PANEL + 0 * TB, 32768);
    stage(Bpan + 1 * PANEL + 0 * TB, 49152);
    stage(Apan + 0 * PANEL + 1 * TB, 65536);
    stage(Apan + 1 * PANEL + 1 * TB, 81920);
    VMC4();                                 // tile 0 resident; A(1) in flight
    BAR();

    #define RD(off) (*(const bf16x8*)(smem + (off)))

    for (int kt = 0; kt < KSTEPS; ++kt) {
        int db  = (kt & 1) << 16;
        int sdb = db ^ 65536;
        int kt1 = kt + 1 < KSTEPS ? kt + 1 : KSTEPS - 1;
        int kt2 = kt + 2 < KSTEPS ? kt + 2 : KSTEPS - 1;

        // ---- phase 1: q0 = (m0-3, n0-1) ----
        #pragma unroll
        for (int mi = 0; mi < 4; ++mi) {
            af[mi * 2 + 0] = RD(db + aoff + mi * 2048 + kx0);
            af[mi * 2 + 1] = RD(db + aoff + mi * 2048 + kx1);
        }
        #pragma unroll
        for (int ni = 0; ni < 2; ++ni) {
            bl[ni * 2 + 0] = RD(db + boff + ni * 2048 + kx0);
            bl[ni * 2 + 1] = RD(db + boff + ni * 2048 + kx1);
        }
        stage(Bpan + 0 * PANEL + kt1 * TB, sdb + 32768);   // B0(kt+1)
        BAR(); LGK0(); SCHED0();
        PRIO1();
        #pragma unroll
        for (int mi = 0; mi < 4; ++mi)
            #pragma unroll
            for (int ni = 0; ni < 2; ++ni) {
                acc[mi][ni] = __builtin_amdgcn_mfma_f32_16x16x32_bf16(
                    af[mi * 2 + 0], bl[ni * 2 + 0], acc[mi][ni], 0, 0, 0);
                acc[mi][ni] = __builtin_amdgcn_mfma_f32_16x16x32_bf16(
                    af[mi * 2 + 1], bl[ni * 2 + 1], acc[mi][ni], 0, 0, 0);
            }
        PRIO0();
        BAR();

        // ---- phase 2: q1 = (m0-3, n2-3) ----
        #pragma unroll
        for (int ni = 0; ni < 2; ++ni) {
            bh[ni * 2 + 0] = RD(db + boff + (ni + 2) * 2048 + kx0);
            bh[ni * 2 + 1] = RD(db + boff + (ni + 2) * 2048 + kx1);
        }
        stage(Bpan + 1 * PANEL + kt1 * TB, sdb + 49152);   // B1(kt+1)
        BAR(); LGK0(); SCHED0();
        PRIO1();
        #pragma unroll
        for (int mi = 0; mi < 4; ++mi)
            #pragma unroll
            for (int ni = 0; ni < 2; ++ni) {
                acc[mi][ni + 2] = __builtin_amdgcn_mfma_f32_16x16x32_bf16(
                    af[mi * 2 + 0], bh[ni * 2 + 0], acc[mi][ni + 2], 0, 0, 0);
                acc[mi][ni + 2] = __builtin_amdgcn_mfma_f32_16x16x32_bf16(
                    af[mi * 2 + 1], bh[ni * 2 + 1], acc[mi][ni + 2], 0, 0, 0);
            }
        PRIO0();
        BAR();

        // ---- phase 3: q2 = (m4-7, n0-1) ----
        #pragma unroll
        for (int mi = 0; mi < 4; ++mi) {
            af[mi * 2 + 0] = RD(db + aoff + (mi + 4) * 2048 + kx0);
            af[mi * 2 + 1] = RD(db + aoff + (mi + 4) * 2048 + kx1);
        }
        BAR(); LGK0(); SCHED0();
        PRIO1();
        #pragma unroll
        for (int mi = 0; mi < 4; ++mi)
            #pragma unroll
            for (int ni = 0; ni < 2; ++ni) {
                acc[mi + 4][ni] = __builtin_amdgcn_mfma_f32_16x16x32_bf16(
                    af[mi * 2 + 0], bl[ni * 2 + 0], acc[mi + 4][ni], 0, 0, 0);
                acc[mi + 4][ni] = __builtin_amdgcn_mfma_f32_16x16x32_bf16(
                    af[mi * 2 + 1], bl[ni * 2 + 1], acc[mi + 4][ni], 0, 0, 0);
            }
        PRIO0();
        BAR();

        // ---- phase 4: q3 = (m4-7, n2-3) ----
        stage(Apan + 0 * PANEL + kt2 * TB, db);            // A0(kt+2)
        stage(Apan + 1 * PANEL + kt2 * TB, db + 16384);    // A1(kt+2)
        BAR();
        PRIO1();
        #pragma unroll
        for (int mi = 0; mi < 4; ++mi)
            #pragma unroll
            for (int ni = 0; ni < 2; ++ni) {
                acc[mi + 4][ni + 2] = __builtin_amdgcn_mfma_f32_16x16x32_bf16(
                    af[mi * 2 + 0], bh[ni * 2 + 0], acc[mi + 4][ni + 2], 0, 0, 0);
                acc[mi + 4][ni + 2] = __builtin_amdgcn_mfma_f32_16x16x32_bf16(
                    af[mi * 2 + 1], bh[ni * 2 + 1], acc[mi + 4][ni + 2], 0, 0, 0);
            }
        PRIO0();
        VMC4();    // retire tile kt+1 halves; keep A(kt+2) in flight
        BAR();
    }

    // epilogue: bias + phase-shift scatter
    int M0 = mb * 256 + wm * 128;
    int N0 = nb * 256 + wn * 64;
    int nlane = lane & 15;
    int mrow  = (lane >> 4) * 4;

    #pragma unroll
    for (int ni = 0; ni < 4; ++ni) {
        int n  = N0 + ni * 16 + nlane;
        float bv = bias[n];
        int cc  = n & 63;
        int nch = n >> 6;
        int i_hi = (cc >> 1) << 3;
        int j_hi = (cc & 1) << 7;
        #pragma unroll
        for (int mi = 0; mi < 8; ++mi) {
            #pragma unroll
            for (int r = 0; r < 4; ++r) {
                int m = M0 + mi * 16 + mrow + r;
                int b = m >> 10, h = (m >> 5) & 31, w = m & 31;
                int i = i_hi | (w & 7);
                int j = j_hi | ((h >> 1) << 3) | ((h & 1) << 2) | (w >> 3);
                out[((size_t)b * 152 + nch) * 65536 + i * 256 + j] =
                    acc[mi][ni][r] + bv;
            }
        }
    }
}

extern "C" void kernel_launch(void* const* d_in, const int* in_sizes, int n_in,
                              void* d_out, int out_size, void* d_ws, size_t ws_size,
                              hipStream_t stream) {
    const float* x    = (const float*)d_in[0];
    const float* Wt   = (const float*)d_in[1];
    const float* bias = (const float*)d_in[2];
    float* out        = (float*)d_out;

    const size_t needW = (size_t)76 * PANEL;  // 89,653,248
    const size_t needA = (size_t)32 * PANEL;  // 37,748,736

    if (ws_size >= needW + needA) {
        __bf16* Wws = (__bf16*)d_ws;
        __bf16* Aws = (__bf16*)((char*)d_ws + needW);
        pack_W<<<21888, 256, 0, stream>>>(Wt, Wws);
        pack_A<<<9216, 256, 0, stream>>>(x, Aws);
        gemm_ps<<<MB256 * NB256, 512, 0, stream>>>(Aws, Wws, bias, out);
    } else {
        const int total = NBAT * COUT * 1024;
        conv_ps_direct<<<total / 256, 256, 0, stream>>>(x, Wt, bias, out);
    }
}

// Round 5
// 538.876 us; speedup vs baseline: 1.0206x; 1.0206x over previous
//
#include <hip/hip_runtime.h>

// Group_10: replicate-pad 3x3 conv (4,512,32,32)->(4,9728,32,32) + bias,
// then faithful-PS reinterpretation to (4,152,256,256).
//
// Implicit GEMM, pre-packed bf16 operands (pack_W / pack_A verified on HW:
// absmax 0.031, SQ_LDS_BANK_CONFLICT = 0).
//
// Round 5: 256x256 8-phase with DEEP prefetch. Slot parity: tile t+2 uses
// the same dbuf slot as tile t, so:
//   ph3 of t: stage B0,B1(t+2)  (B(t) reads drained at ph2-end barrier)
//   ph4 of t: stage A0,A1(t+2)  (A(t) reads drained at ph3-end barrier)
//   vmcnt(8) at ph4-end: 8 newest = this tile's (t+2) stages -> confirms
//   everything for t+1 retired; loads stay in flight 4-8 phases, never 0.
// B-regs bl (read ph1) are reused in ph3, bh (ph2) in ph4 - register-held,
// so overwriting the LDS B slot at ph3 is safe.

#define CIN   512
#define COUT  9728
#define NBAT  4
#define KTOT  4608
#define KSTEPS 72           // K = 72 * 64
#define MB256  16           // M = 4096 = 16*256
#define NB256  38           // N = 9728 = 38*256
#define TB     16384        // packed tile: 128 rows x 64 bf16 x 2B
#define PANEL  (KSTEPS * TB)

typedef __bf16 bf16x8 __attribute__((ext_vector_type(8)));
typedef float  f32x4  __attribute__((ext_vector_type(4)));

#define BAR()   __builtin_amdgcn_s_barrier()
#define LGK0()  asm volatile("s_waitcnt lgkmcnt(0)" ::: "memory")
#define LGK8()  asm volatile("s_waitcnt lgkmcnt(8)" ::: "memory")
#define VMC8()  asm volatile("s_waitcnt vmcnt(8)" ::: "memory")
#define SCHED0() __builtin_amdgcn_sched_barrier(0)
#define PRIO1() __builtin_amdgcn_s_setprio(1)
#define PRIO0() __builtin_amdgcn_s_setprio(0)

// ---------------- fallback: direct conv (correct, slow) ----------------
__global__ __launch_bounds__(256) void conv_ps_direct(
    const float* __restrict__ x, const float* __restrict__ Wt,
    const float* __restrict__ bias, float* __restrict__ out)
{
    int flat = blockIdx.x * 256 + threadIdx.x;
    int w  = flat & 31;
    int h  = (flat >> 5) & 31;
    int t  = flat >> 10;
    int co = t % COUT;
    int b  = t / COUT;

    const float* xb = x + (size_t)b * CIN * 1024;
    const float* Wc = Wt + (size_t)co * CIN * 9;

    int hm = h > 0  ? h - 1 : 0;
    int hp = h < 31 ? h + 1 : 31;
    int wm = w > 0  ? w - 1 : 0;
    int wp = w < 31 ? w + 1 : 31;

    float acc = bias[co];
    #pragma unroll 4
    for (int ci = 0; ci < CIN; ++ci) {
        const float* xc = xb + ci * 1024;
        const float* wf = Wc + ci * 9;
        const float* r0 = xc + hm * 32;
        const float* r1 = xc + h  * 32;
        const float* r2 = xc + hp * 32;
        acc += wf[0] * r0[wm] + wf[1] * r0[w] + wf[2] * r0[wp];
        acc += wf[3] * r1[wm] + wf[4] * r1[w] + wf[5] * r1[wp];
        acc += wf[6] * r2[wm] + wf[7] * r2[w] + wf[8] * r2[wp];
    }
    int cc = co & 63;
    int n  = co >> 6;
    int i  = ((cc >> 1) << 3) | (w & 7);
    int j  = ((cc & 1) << 7) | ((h >> 1) << 3) | ((h & 1) << 2) | (w >> 3);
    out[(((size_t)b * 152 + n) * 256 + i) * 256 + j] = acc;
}

// ---------------- pack W: fp32 -> bf16, tiled + swizzled ----------------
__global__ __launch_bounds__(256) void pack_W(const float* __restrict__ Wt,
                                              __bf16* __restrict__ Wws)
{
    int G = blockIdx.x * 256 + threadIdx.x;   // < 76*72*128*8
    int s    = G & 7;
    int r    = (G >> 3) & 127;
    int rest = G >> 10;                        // nb128*72 + kt
    int kt = rest % KSTEPS;
    int nb = rest / KSTEPS;
    int n  = nb * 128 + r;
    int g  = s ^ (r & 7);
    int k0 = kt * 64 + g * 8;

    const float* src = Wt + (size_t)n * KTOT + k0;
    float4 v0 = *(const float4*)(src);
    float4 v1 = *(const float4*)(src + 4);
    bf16x8 o;
    o[0] = (__bf16)v0.x; o[1] = (__bf16)v0.y; o[2] = (__bf16)v0.z; o[3] = (__bf16)v0.w;
    o[4] = (__bf16)v1.x; o[5] = (__bf16)v1.y; o[6] = (__bf16)v1.z; o[7] = (__bf16)v1.w;
    *(bf16x8*)(Wws + (size_t)G * 8) = o;
}

// ---------------- pack A: im2col bf16, same tiling/swizzle ----------------
__global__ __launch_bounds__(256) void pack_A(const float* __restrict__ x,
                                              __bf16* __restrict__ Aws)
{
    int G = blockIdx.x * 256 + threadIdx.x;   // < 32*72*128*8
    int s    = G & 7;
    int r    = (G >> 3) & 127;
    int rest = G >> 10;                        // mb128*72 + kt
    int kt = rest % KSTEPS;
    int mb = rest / KSTEPS;
    int m  = mb * 128 + r;
    int b  = m >> 10;
    int h  = (m >> 5) & 31;
    int w  = m & 31;
    int g  = s ^ (r & 7);
    int k0 = kt * 64 + g * 8;

    const float* xb = x + (size_t)b * CIN * 1024;
    bf16x8 o;
    #pragma unroll
    for (int e = 0; e < 8; ++e) {
        int k  = k0 + e;
        int ci = k / 9;
        int r9 = k - ci * 9;
        int kh = r9 / 3;
        int kw = r9 - kh * 3;
        int hh = h + kh - 1; hh = hh < 0 ? 0 : (hh > 31 ? 31 : hh);
        int ww = w + kw - 1; ww = ww < 0 ? 0 : (ww > 31 ? 31 : ww);
        o[e] = (__bf16)xb[(ci << 10) + (hh << 5) + ww];
    }
    *(bf16x8*)(Aws + (size_t)G * 8) = o;
}

// ---------------- 256x256 8-phase GEMM + fused PS epilogue ----------------
__global__ __launch_bounds__(512, 2) void gemm_ps(
    const __bf16* __restrict__ Aws, const __bf16* __restrict__ Wws,
    const float* __restrict__ bias, float* __restrict__ out)
{
    // LDS: slot d at d*65536; A halves at +0/+16384; B halves at +32768/+49152
    __shared__ __align__(16) char smem[131072];

    // XCD-bijective swizzle: 608 blocks = 8 * 76
    int bid = blockIdx.x;
    int g   = (bid & 7) * 76 + (bid >> 3);
    int mb  = g & 15;
    int nb  = g >> 4;

    int t    = threadIdx.x;
    int lane = t & 63;
    int wid  = t >> 6;
    int wm = wid >> 2, wn = wid & 3;      // 2x4 waves; wave tile 128x64

    const char* Apan = (const char*)Aws + (size_t)(mb * 2) * PANEL;
    const char* Bpan = (const char*)Wws + (size_t)(nb * 2) * PANEL;
    int t16 = t * 16;

    auto stage = [&](const char* srcTile, int ldsOff) {
        __builtin_amdgcn_global_load_lds(
            (const __attribute__((address_space(1))) void*)(srcTile + t16),
            (__attribute__((address_space(3))) void*)(smem + ldsOff + t16), 16, 0, 0);
        __builtin_amdgcn_global_load_lds(
            (const __attribute__((address_space(1))) void*)(srcTile + 8192 + t16),
            (__attribute__((address_space(3))) void*)(smem + ldsOff + 8192 + t16), 16, 0, 0);
    };

    // swizzled ds_read offsets (swizzle pre-baked in global layout)
    int aoff = wm * 16384 + (lane & 15) * 128;
    int boff = 32768 + (wn >> 1) * 16384 + (((wn & 1) << 6) + (lane & 15)) * 128;
    int kx0  = (((lane >> 4)    ) ^ (lane & 7)) << 4;
    int kx1  = (((lane >> 4) + 4) ^ (lane & 7)) << 4;

    f32x4 acc[8][4] = {};
    bf16x8 af[8], bl[4], bh[4];

    // prologue: tiles 0 and 1 fully staged; vmcnt(8) keeps tile 1 in flight
    stage(Apan + 0 * PANEL + 0 * TB, 0);
    stage(Apan + 1 * PANEL + 0 * TB, 16384);
    stage(Bpan + 0 * PANEL + 0 * TB, 32768);
    stage(Bpan + 1 * PANEL + 0 * TB, 49152);
    stage(Apan + 0 * PANEL + 1 * TB, 65536);
    stage(Apan + 1 * PANEL + 1 * TB, 81920);
    stage(Bpan + 0 * PANEL + 1 * TB, 98304);
    stage(Bpan + 1 * PANEL + 1 * TB, 114688);
    VMC8();                                 // tile 0 resident; tile 1 in flight
    BAR();

    #define RD(off) (*(const bf16x8*)(smem + (off)))

    for (int kt = 0; kt < KSTEPS; ++kt) {
        int db  = (kt & 1) << 16;
        int kt2 = kt + 2 < KSTEPS ? kt + 2 : KSTEPS - 1;   // clamp: harmless re-stage

        // ---- phase 1: q0 = (m0-3, n0-1) ----
        #pragma unroll
        for (int mi = 0; mi < 4; ++mi) {
            af[mi * 2 + 0] = RD(db + aoff + mi * 2048 + kx0);
            af[mi * 2 + 1] = RD(db + aoff + mi * 2048 + kx1);
        }
        #pragma unroll
        for (int ni = 0; ni < 2; ++ni) {
            bl[ni * 2 + 0] = RD(db + boff + ni * 2048 + kx0);
            bl[ni * 2 + 1] = RD(db + boff + ni * 2048 + kx1);
        }
        LGK8();
        BAR(); LGK0(); SCHED0();
        PRIO1();
        #pragma unroll
        for (int mi = 0; mi < 4; ++mi)
            #pragma unroll
            for (int ni = 0; ni < 2; ++ni) {
                acc[mi][ni] = __builtin_amdgcn_mfma_f32_16x16x32_bf16(
                    af[mi * 2 + 0], bl[ni * 2 + 0], acc[mi][ni], 0, 0, 0);
                acc[mi][ni] = __builtin_amdgcn_mfma_f32_16x16x32_bf16(
                    af[mi * 2 + 1], bl[ni * 2 + 1], acc[mi][ni], 0, 0, 0);
            }
        PRIO0();
        BAR();

        // ---- phase 2: q1 = (m0-3, n2-3) ----
        #pragma unroll
        for (int ni = 0; ni < 2; ++ni) {
            bh[ni * 2 + 0] = RD(db + boff + (ni + 2) * 2048 + kx0);
            bh[ni * 2 + 1] = RD(db + boff + (ni + 2) * 2048 + kx1);
        }
        BAR(); LGK0(); SCHED0();
        PRIO1();
        #pragma unroll
        for (int mi = 0; mi < 4; ++mi)
            #pragma unroll
            for (int ni = 0; ni < 2; ++ni) {
                acc[mi][ni + 2] = __builtin_amdgcn_mfma_f32_16x16x32_bf16(
                    af[mi * 2 + 0], bh[ni * 2 + 0], acc[mi][ni + 2], 0, 0, 0);
                acc[mi][ni + 2] = __builtin_amdgcn_mfma_f32_16x16x32_bf16(
                    af[mi * 2 + 1], bh[ni * 2 + 1], acc[mi][ni + 2], 0, 0, 0);
            }
        PRIO0();
        BAR();

        // ---- phase 3: q2 = (m4-7, n0-1); stage B(t+2) into this slot ----
        #pragma unroll
        for (int mi = 0; mi < 4; ++mi) {
            af[mi * 2 + 0] = RD(db + aoff + (mi + 4) * 2048 + kx0);
            af[mi * 2 + 1] = RD(db + aoff + (mi + 4) * 2048 + kx1);
        }
        stage(Bpan + 0 * PANEL + kt2 * TB, db + 32768);
        stage(Bpan + 1 * PANEL + kt2 * TB, db + 49152);
        BAR(); LGK0(); SCHED0();
        PRIO1();
        #pragma unroll
        for (int mi = 0; mi < 4; ++mi)
            #pragma unroll
            for (int ni = 0; ni < 2; ++ni) {
                acc[mi + 4][ni] = __builtin_amdgcn_mfma_f32_16x16x32_bf16(
                    af[mi * 2 + 0], bl[ni * 2 + 0], acc[mi + 4][ni], 0, 0, 0);
                acc[mi + 4][ni] = __builtin_amdgcn_mfma_f32_16x16x32_bf16(
                    af[mi * 2 + 1], bl[ni * 2 + 1], acc[mi + 4][ni], 0, 0, 0);
            }
        PRIO0();
        BAR();

        // ---- phase 4: q3 = (m4-7, n2-3); stage A(t+2); vmcnt(8) ----
        stage(Apan + 0 * PANEL + kt2 * TB, db);
        stage(Apan + 1 * PANEL + kt2 * TB, db + 16384);
        BAR();
        PRIO1();
        #pragma unroll
        for (int mi = 0; mi < 4; ++mi)
            #pragma unroll
            for (int ni = 0; ni < 2; ++ni) {
                acc[mi + 4][ni + 2] = __builtin_amdgcn_mfma_f32_16x16x32_bf16(
                    af[mi * 2 + 0], bh[ni * 2 + 0], acc[mi + 4][ni + 2], 0, 0, 0);
                acc[mi + 4][ni + 2] = __builtin_amdgcn_mfma_f32_16x16x32_bf16(
                    af[mi * 2 + 1], bh[ni * 2 + 1], acc[mi + 4][ni + 2], 0, 0, 0);
            }
        PRIO0();
        VMC8();    // 8 newest = this tile's (t+2) stages -> tile t+1 confirmed
        BAR();
    }

    // epilogue: bias + phase-shift scatter
    int M0 = mb * 256 + wm * 128;
    int N0 = nb * 256 + wn * 64;
    int nlane = lane & 15;
    int mrow  = (lane >> 4) * 4;

    #pragma unroll
    for (int ni = 0; ni < 4; ++ni) {
        int n  = N0 + ni * 16 + nlane;
        float bv = bias[n];
        int cc  = n & 63;
        int nch = n >> 6;
        int i_hi = (cc >> 1) << 3;
        int j_hi = (cc & 1) << 7;
        #pragma unroll
        for (int mi = 0; mi < 8; ++mi) {
            #pragma unroll
            for (int r = 0; r < 4; ++r) {
                int m = M0 + mi * 16 + mrow + r;
                int b = m >> 10, h = (m >> 5) & 31, w = m & 31;
                int i = i_hi | (w & 7);
                int j = j_hi | ((h >> 1) << 3) | ((h & 1) << 2) | (w >> 3);
                out[((size_t)b * 152 + nch) * 65536 + i * 256 + j] =
                    acc[mi][ni][r] + bv;
            }
        }
    }
}

extern "C" void kernel_launch(void* const* d_in, const int* in_sizes, int n_in,
                              void* d_out, int out_size, void* d_ws, size_t ws_size,
                              hipStream_t stream) {
    const float* x    = (const float*)d_in[0];
    const float* Wt   = (const float*)d_in[1];
    const float* bias = (const float*)d_in[2];
    float* out        = (float*)d_out;

    const size_t needW = (size_t)76 * PANEL;  // 89,653,248
    const size_t needA = (size_t)32 * PANEL;  // 37,748,736

    if (ws_size >= needW + needA) {
        __bf16* Wws = (__bf16*)d_ws;
        __bf16* Aws = (__bf16*)((char*)d_ws + needW);
        pack_W<<<21888, 256, 0, stream>>>(Wt, Wws);
        pack_A<<<9216, 256, 0, stream>>>(x, Aws);
        gemm_ps<<<MB256 * NB256, 512, 0, stream>>>(Aws, Wws, bias, out);
    } else {
        const int total = NBAT * COUT * 1024;
        conv_ps_direct<<<total / 256, 256, 0, stream>>>(x, Wt, bias, out);
    }
}